// Round 1
// 451.023 us; speedup vs baseline: 1.0656x; 1.0656x over previous
//
#include <hip/hip_runtime.h>
#include <hip/hip_bf16.h>

#define NN 384
#define HIDDIM 128
#define NHEADS 8
#define HD 16
#define LOCAL_E (NN*NN)          // 147456
#define NE (2*LOCAL_E)           // 294912 edges
#define NNODE (2*NN)             // 768

typedef __attribute__((ext_vector_type(8))) __bf16 bf16x8;
typedef __attribute__((ext_vector_type(4))) float f32x4;

// ---------------------------------------------------------------------------
// prep: pack [W_edge | W_gate] (128x256 fp32) into bf16 MFMA fragment granules
// granules: layout [kkh(2)][n'(16)][kkl(2)][quad(4)][n16(16)] x 8 bf16.
// granule content: W_cat[k = (kkh*2+kkl)*32 + quad*8 + j][n = n'*16+n16]
// (A-frag and B-frag lane layouts are index-symmetric, so these granules can
//  serve as A-fragments of W_cat^T directly.)
// ---------------------------------------------------------------------------
__global__ void prep_w(const float* __restrict__ W_edge, const float* __restrict__ W_gate,
                       bf16x8* __restrict__ Wg) {
    int gid = blockIdx.x * blockDim.x + threadIdx.x;   // 0..4095
    int n16  = gid & 15;
    int quad = (gid >> 4) & 3;
    int kkl  = (gid >> 6) & 1;
    int np   = (gid >> 7) & 15;
    int kkh  = (gid >> 11) & 1;
    int n = np * 16 + n16;
    int k0 = (kkh * 2 + kkl) * 32 + quad * 8;
    const float* src = (n < 128) ? (W_edge + n) : (W_gate + (n - 128));
    bf16x8 v;
#pragma unroll
    for (int j = 0; j < 8; ++j) v[j] = (__bf16)src[(size_t)(k0 + j) * 128];
    Wg[gid] = v;
}

// ---------------------------------------------------------------------------
// K1: h = nf@W_node + b ; Q/K/V = h@W_{q,k,v} + b   (fp32, tiny)
// Q/K/V stored as (B, NH, N, HD) for K3 locality. 8 rows per 128-thr block.
// ---------------------------------------------------------------------------
__global__ __launch_bounds__(128) void k1_proj(
    const float* __restrict__ nf,
    const float* __restrict__ Wn, const float* __restrict__ bn,
    const float* __restrict__ Wq, const float* __restrict__ bq,
    const float* __restrict__ Wk, const float* __restrict__ bk,
    const float* __restrict__ Wv, const float* __restrict__ bv,
    float* __restrict__ h_res, float* __restrict__ Q,
    float* __restrict__ K, float* __restrict__ V)
{
    __shared__ float xf[8][128];
    __shared__ float hf[8][128];
    int t = threadIdx.x;
    int r0 = blockIdx.x * 8;
    for (int r = 0; r < 8; ++r) xf[r][t] = nf[(size_t)(r0 + r) * 128 + t];
    __syncthreads();
    float acc[8];
#pragma unroll
    for (int r = 0; r < 8; ++r) acc[r] = bn[t];
    for (int k = 0; k < 128; ++k) {
        float w = Wn[k * 128 + t];
#pragma unroll
        for (int r = 0; r < 8; ++r) acc[r] += xf[r][k] * w;
    }
    for (int r = 0; r < 8; ++r) { h_res[(size_t)(r0 + r) * 128 + t] = acc[r]; hf[r][t] = acc[r]; }
    __syncthreads();
    const float* Ws[3] = {Wq, Wk, Wv};
    const float* bs[3] = {bq, bk, bv};
    float* Os[3] = {Q, K, V};
#pragma unroll
    for (int m = 0; m < 3; ++m) {
        float a2[8];
#pragma unroll
        for (int r = 0; r < 8; ++r) a2[r] = bs[m][t];
        for (int k = 0; k < 128; ++k) {
            float w = Ws[m][k * 128 + t];
#pragma unroll
            for (int r = 0; r < 8; ++r) a2[r] += hf[r][k] * w;
        }
        int hh = t >> 4, d = t & 15;
        for (int r = 0; r < 8; ++r) {
            int g = r0 + r;
            int b = g / NN, i = g - b * NN;
            Os[m][(size_t)((b * NHEADS + hh) * NN + i) * HD + d] = a2[r];
        }
    }
}

// ---------------------------------------------------------------------------
// K2: edge_attn[b,h,i,j] = sum_d ( (E@W_edge+b_e) * sigmoid(E@W_gate+b_g) )
// MFMA bf16 16x16x32 with SWAPPED operands: C[hid][edge] = W_cat^T (A) x E^T (B).
// C layout (col=lane&15, row=quad*4+r) puts 4 d-values of ONE head for ONE
// edge in each lane -> the gated product + d-reduction is 3 in-reg adds +
// 2 shuffles per OUTPUT (vs 4 shfl + 4 add per PRODUCT before).
// Wave w owns head w (h-tile w, gate-tile w+8). W fragments live in registers
// (loaded once from L3-hot Wg); LDS holds the full 128x128 E tile (bf16,
// fragment-granule order, 32 KB) -> ONE barrier per block.
// ---------------------------------------------------------------------------
__global__ __launch_bounds__(512, 4) void k2_edge(
    const float* __restrict__ EF, const bf16x8* __restrict__ Wg,
    const float* __restrict__ b_edge, const float* __restrict__ b_gate,
    float* __restrict__ edge_attn)
{
    __shared__ bf16x8 Ash[2048];   // 32 KB: full 128(M) x 128(K) E tile
    int t = threadIdx.x;
    int lane = t & 63;
    int w = t >> 6;                // wave id == head id
    int e_base = blockIdx.x * 128;

    // W fragments for this wave's head: h part (cols w*16..) and gate part
    // (cols (w+8)*16..). kk = kkh*2+kkl indexes the four K=32 slices.
    bf16x8 wfh[4], wfg[4];
#pragma unroll
    for (int kk = 0; kk < 4; ++kk) {
        int kkh = kk >> 1, kkl = kk & 1;
        wfh[kk] = Wg[kkh * 2048 + ( w      * 2 + kkl) * 64 + lane];
        wfg[kk] = Wg[kkh * 2048 + ((w + 8) * 2 + kkl) * 64 + lane];
    }

    // stage E tile: fp32 -> bf16 into fragment granules (4 granules/thread)
#pragma unroll
    for (int p = 0; p < 4; ++p) {
        int gid = p * 512 + t;
        int m16 = gid & 15, quad = (gid >> 4) & 3, kk = (gid >> 6) & 3, ip = gid >> 8;
        int row = ip * 16 + m16;
        const float4* src4 = (const float4*)(EF + (size_t)(e_base + row) * 128
                                             + kk * 32 + quad * 8);
        float4 f0 = src4[0], f1 = src4[1];
        bf16x8 v;
        v[0] = (__bf16)f0.x; v[1] = (__bf16)f0.y; v[2] = (__bf16)f0.z; v[3] = (__bf16)f0.w;
        v[4] = (__bf16)f1.x; v[5] = (__bf16)f1.y; v[6] = (__bf16)f1.z; v[7] = (__bf16)f1.w;
        Ash[gid] = v;
    }
    __syncthreads();

    f32x4 acc_h[8], acc_g[8];
    f32x4 zero = {0.f, 0.f, 0.f, 0.f};
#pragma unroll
    for (int ip = 0; ip < 8; ++ip) { acc_h[ip] = zero; acc_g[ip] = zero; }

#pragma unroll
    for (int kk = 0; kk < 4; ++kk) {
#pragma unroll
        for (int ip = 0; ip < 8; ++ip) {
            bf16x8 be = Ash[(ip * 4 + kk) * 64 + lane];
            acc_h[ip] = __builtin_amdgcn_mfma_f32_16x16x32_bf16(wfh[kk], be, acc_h[ip], 0, 0, 0);
            acc_g[ip] = __builtin_amdgcn_mfma_f32_16x16x32_bf16(wfg[kk], be, acc_g[ip], 0, 0, 0);
        }
    }

    // epilogue: lane-local gated product over 4 d-values, then 2-shuffle
    // cross-quad reduce (d = quad*4 + r).
    int n16 = lane & 15, quad = lane >> 4;
    float bh[4], bg[4];
#pragma unroll
    for (int r = 0; r < 4; ++r) {
        bh[r] = b_edge[w * 16 + quad * 4 + r];
        bg[r] = b_gate[w * 16 + quad * 4 + r];
    }
#pragma unroll
    for (int ip = 0; ip < 8; ++ip) {
        float s = 0.f;
#pragma unroll
        for (int r = 0; r < 4; ++r) {
            float hv = acc_h[ip][r] + bh[r];
            float gv = acc_g[ip][r] + bg[r];
            float sig = __builtin_amdgcn_rcpf(1.f + __expf(-gv));
            s = fmaf(hv, sig, s);
        }
        s += __shfl_xor(s, 16);
        s += __shfl_xor(s, 32);
        if (quad == 0) {   // lanes 0..15 hold the full sum for edge n16
            int e = e_base + ip * 16 + n16;
            int b = e / LOCAL_E;
            int local = e - b * LOCAL_E;
            edge_attn[(size_t)(b * NHEADS + w) * LOCAL_E + local] = s;
        }
    }
}

// ---------------------------------------------------------------------------
// K3: scores = QK^T/4 + edge_attn, mask, softmax, attn_out = attn@V,
// attn_mean accumulated via atomics (zeroed beforehand).
// Block: 128 thr handles (b,h, 16 query rows). K/V for the head in LDS.
// ---------------------------------------------------------------------------
__global__ __launch_bounds__(128) void k3_attn(
    const float* __restrict__ Q, const float* __restrict__ K, const float* __restrict__ V,
    const float* __restrict__ edge_attn, const int* __restrict__ adj,
    float* __restrict__ am, float* __restrict__ attn_out)
{
    __shared__ float Kh[NN * 17];
    __shared__ float Vh[NN * 17];
    __shared__ float Qi[16 * HD];
    __shared__ float rowbuf[NN];
    __shared__ float red[2];
    __shared__ float red2[8][16];
    int t = threadIdx.x;
    int bh = blockIdx.x / 24;
    int chunk = blockIdx.x % 24;
    int b = bh >> 3;
    const float* Kbase = K + (size_t)bh * NN * HD;
    const float* Vbase = V + (size_t)bh * NN * HD;
    for (int p = 0; p < 48; ++p) {
        int idx = p * 128 + t;
        int jj = idx >> 4, dd = idx & 15;
        Kh[jj * 17 + dd] = Kbase[idx];
        Vh[jj * 17 + dd] = Vbase[idx];
    }
    Qi[t]       = Q[(size_t)bh * NN * HD + chunk * 16 * HD + t];
    Qi[t + 128] = Q[(size_t)bh * NN * HD + chunk * 16 * HD + t + 128];
    __syncthreads();
    int lane = t & 63, wid = t >> 6;
    const float* ea = edge_attn + (size_t)bh * LOCAL_E;
    const int* adjb = adj + (size_t)b * LOCAL_E;
    for (int rr = 0; rr < 16; ++rr) {
        int i = chunk * 16 + rr;
        float s[3];
#pragma unroll
        for (int jj = 0; jj < 3; ++jj) {
            int j = t + jj * 128;
            float a = 0.f;
#pragma unroll
            for (int d = 0; d < 16; ++d) a += Qi[rr * 16 + d] * Kh[j * 17 + d];
            a = a * 0.25f + ea[(size_t)i * NN + j];
            if (adjb[(size_t)i * NN + j] == 0) a = -1e9f;
            s[jj] = a;
        }
        float mx = fmaxf(s[0], fmaxf(s[1], s[2]));
#pragma unroll
        for (int o = 1; o < 64; o <<= 1) mx = fmaxf(mx, __shfl_xor(mx, o));
        if (lane == 0) red[wid] = mx;
        __syncthreads();
        mx = fmaxf(red[0], red[1]);
        __syncthreads();
        float e0 = __expf(s[0] - mx), e1 = __expf(s[1] - mx), e2 = __expf(s[2] - mx);
        float sm = e0 + e1 + e2;
#pragma unroll
        for (int o = 1; o < 64; o <<= 1) sm += __shfl_xor(sm, o);
        if (lane == 0) red[wid] = sm;
        __syncthreads();
        float inv = 1.f / (red[0] + red[1]);
        float p0 = e0 * inv, p1 = e1 * inv, p2 = e2 * inv;
        rowbuf[t] = p0; rowbuf[t + 128] = p1; rowbuf[t + 256] = p2;
        atomicAdd(am + (size_t)b * LOCAL_E + i * NN + t,       p0 * 0.125f);
        atomicAdd(am + (size_t)b * LOCAL_E + i * NN + t + 128, p1 * 0.125f);
        atomicAdd(am + (size_t)b * LOCAL_E + i * NN + t + 256, p2 * 0.125f);
        __syncthreads();
        int d = t & 15, g = t >> 4;
        float pa = 0.f;
        for (int j = g * 48; j < g * 48 + 48; ++j) pa += rowbuf[j] * Vh[j * 17 + d];
        red2[g][d] = pa;
        __syncthreads();
        if (t < 16) {
            float s2 = 0.f;
#pragma unroll
            for (int gg = 0; gg < 8; ++gg) s2 += red2[gg][t];
            attn_out[(size_t)(b * NN + i) * HIDDIM + (bh & 7) * HD + t] = s2;
        }
        __syncthreads();
    }
}

// ---------------------------------------------------------------------------
// K5: h_new = LN(residual + attn_out@W_out + b_out); hp = h_new@W_eout
// ---------------------------------------------------------------------------
__global__ __launch_bounds__(128) void k5_hout(
    const float* __restrict__ attn_out, const float* __restrict__ h_res,
    const float* __restrict__ W_out, const float* __restrict__ b_out,
    const float* __restrict__ g1, const float* __restrict__ be1,
    const float* __restrict__ W_eout,
    float* __restrict__ h_out, float* __restrict__ hp)
{
    __shared__ float ao[8][128];
    __shared__ float hn[8][128];
    __shared__ float redA[2], redB[2];
    int t = threadIdx.x, r0 = blockIdx.x * 8;
    for (int r = 0; r < 8; ++r) ao[r][t] = attn_out[(size_t)(r0 + r) * 128 + t];
    __syncthreads();
    float acc[8];
#pragma unroll
    for (int r = 0; r < 8; ++r) acc[r] = b_out[t];
    for (int k = 0; k < 128; ++k) {
        float w = W_out[k * 128 + t];
#pragma unroll
        for (int r = 0; r < 8; ++r) acc[r] += ao[r][k] * w;
    }
    int lane = t & 63, wid = t >> 6;
    float gg = g1[t], bb = be1[t];
    for (int r = 0; r < 8; ++r) {
        float u = h_res[(size_t)(r0 + r) * 128 + t] + acc[r];
        float sv = u, sq = u * u;
#pragma unroll
        for (int o = 1; o < 64; o <<= 1) { sv += __shfl_xor(sv, o); sq += __shfl_xor(sq, o); }
        if (lane == 0) { redA[wid] = sv; redB[wid] = sq; }
        __syncthreads();
        float tot = redA[0] + redA[1], totq = redB[0] + redB[1];
        __syncthreads();
        float mean = tot * (1.f / 128.f);
        float var = totq * (1.f / 128.f) - mean * mean;
        float nv = (u - mean) * rsqrtf(var + 1e-5f) * gg + bb;
        h_out[(size_t)(r0 + r) * 128 + t] = nv;
        hn[r][t] = nv;
    }
    __syncthreads();
    float acc2[8];
#pragma unroll
    for (int r = 0; r < 8; ++r) acc2[r] = 0.f;
    for (int k = 0; k < 128; ++k) {
        float w = W_eout[k * 128 + t];
#pragma unroll
        for (int r = 0; r < 8; ++r) acc2[r] += hn[r][k] * w;
    }
    for (int r = 0; r < 8; ++r) hp[(size_t)(r0 + r) * 128 + t] = acc2[r];
}

// ---------------------------------------------------------------------------
// K6: edge_out = LN(edge_feat + am*0.5*(hp_i+hp_j) + b_eout)  (HBM-bound)
// 8 edges per 256-thr block; 32 lanes x float4 per edge.
// ---------------------------------------------------------------------------
__global__ __launch_bounds__(256) void k6_eout(
    const float* __restrict__ EF, const float* __restrict__ am,
    const float* __restrict__ hp, const float* __restrict__ b_eout,
    const float* __restrict__ g2, const float* __restrict__ be2,
    float* __restrict__ eout)
{
    int t = threadIdx.x;
    int slot = t >> 5, l = t & 31;
    int e = blockIdx.x * 8 + slot;
    int b = e / LOCAL_E;
    int local = e - b * LOCAL_E;
    int i = local / NN, j = local - i * NN;
    float a = am[e];
    const float4* ef4 = (const float4*)(EF + (size_t)e * 128);
    const float4* hpi = (const float4*)(hp + (size_t)(b * NN + i) * 128);
    const float4* hpj = (const float4*)(hp + (size_t)(b * NN + j) * 128);
    float4 ef = ef4[l];
    float4 pi = hpi[l], pj = hpj[l];
    float4 bo = ((const float4*)b_eout)[l];
    float4 u;
    u.x = ef.x + a * 0.5f * (pi.x + pj.x) + bo.x;
    u.y = ef.y + a * 0.5f * (pi.y + pj.y) + bo.y;
    u.z = ef.z + a * 0.5f * (pi.z + pj.z) + bo.z;
    u.w = ef.w + a * 0.5f * (pi.w + pj.w) + bo.w;
    float sv = u.x + u.y + u.z + u.w;
    float sq = u.x * u.x + u.y * u.y + u.z * u.z + u.w * u.w;
#pragma unroll
    for (int o = 1; o < 32; o <<= 1) { sv += __shfl_xor(sv, o); sq += __shfl_xor(sq, o); }
    float mean = sv * (1.f / 128.f);
    float var = sq * (1.f / 128.f) - mean * mean;
    float rs = rsqrtf(var + 1e-5f);
    float4 gg = ((const float4*)g2)[l], bb = ((const float4*)be2)[l];
    float4 o4;
    o4.x = (u.x - mean) * rs * gg.x + bb.x;
    o4.y = (u.y - mean) * rs * gg.y + bb.y;
    o4.z = (u.z - mean) * rs * gg.z + bb.z;
    o4.w = (u.w - mean) * rs * gg.w + bb.w;
    ((float4*)(eout + (size_t)e * 128))[l] = o4;
}

extern "C" void kernel_launch(void* const* d_in, const int* in_sizes, int n_in,
                              void* d_out, int out_size, void* d_ws, size_t ws_size,
                              hipStream_t stream) {
    (void)in_sizes; (void)n_in; (void)out_size; (void)ws_size;
    const float* nf     = (const float*)d_in[0];
    const float* ef     = (const float*)d_in[1];
    const int*   adj    = (const int*)d_in[2];
    const float* W_node = (const float*)d_in[3];
    const float* b_node = (const float*)d_in[4];
    const float* W_q    = (const float*)d_in[5];
    const float* b_q    = (const float*)d_in[6];
    const float* W_k    = (const float*)d_in[7];
    const float* b_k    = (const float*)d_in[8];
    const float* W_v    = (const float*)d_in[9];
    const float* b_v    = (const float*)d_in[10];
    const float* W_edge = (const float*)d_in[11];
    const float* b_edge = (const float*)d_in[12];
    const float* W_gate = (const float*)d_in[13];
    const float* b_gate = (const float*)d_in[14];
    const float* W_out  = (const float*)d_in[15];
    const float* b_out  = (const float*)d_in[16];
    const float* W_eout = (const float*)d_in[17];
    const float* b_eout = (const float*)d_in[18];
    const float* g1     = (const float*)d_in[19];
    const float* be1    = (const float*)d_in[20];
    const float* g2     = (const float*)d_in[21];
    const float* be2    = (const float*)d_in[22];

    float* ws = (float*)d_ws;
    float* h_res    = ws;                 //  98304
    float* Q        = ws + 98304;         //  98304
    float* Kp       = ws + 196608;        //  98304
    float* Vp       = ws + 294912;        //  98304
    float* attn_out = ws + 393216;        //  98304
    float* hp       = ws + 491520;        //  98304
    float* am       = ws + 589824;        // 294912
    bf16x8* Wg      = (bf16x8*)(ws + 884736); // 64 KB, 16B-aligned

    float* h_out = (float*)d_out;                  // output 0: (B,N,HID)
    float* eout  = (float*)d_out + 98304;          // output 1: (B,N,N,EDGE_DIM)
    // edge_attn scratch parked inside the (not-yet-written) edge output region
    float* edge_attn = eout;                       // 2359296 floats, K6 overwrites later

    prep_w<<<dim3(16), dim3(256), 0, stream>>>(W_edge, W_gate, Wg);
    k1_proj<<<dim3(96), dim3(128), 0, stream>>>(nf, W_node, b_node, W_q, b_q,
                                                W_k, b_k, W_v, b_v, h_res, Q, Kp, Vp);
    k2_edge<<<dim3(2304), dim3(512), 0, stream>>>(ef, Wg, b_edge, b_gate, edge_attn);
    hipMemsetAsync((void*)am, 0, (size_t)NE * sizeof(float), stream);
    k3_attn<<<dim3(384), dim3(128), 0, stream>>>(Q, Kp, Vp, edge_attn, adj, am, attn_out);
    k5_hout<<<dim3(96), dim3(128), 0, stream>>>(attn_out, h_res, W_out, b_out,
                                                g1, be1, W_eout, h_out, hp);
    k6_eout<<<dim3(36864), dim3(256), 0, stream>>>(ef, am, hp, b_eout, g2, be2, eout);
}

// Round 2
// 437.794 us; speedup vs baseline: 1.0978x; 1.0302x over previous
//
#include <hip/hip_runtime.h>
#include <hip/hip_bf16.h>

#define NN 384
#define HIDDIM 128
#define NHEADS 8
#define HD 16
#define LOCAL_E (NN*NN)          // 147456
#define NE (2*LOCAL_E)           // 294912 edges
#define NNODE (2*NN)             // 768

typedef __attribute__((ext_vector_type(8))) __bf16 bf16x8;
typedef __attribute__((ext_vector_type(4))) float f32x4;

// ---------------------------------------------------------------------------
// prep: pack [W_edge | W_gate] (128x256 fp32) into bf16 MFMA fragment granules
// granules: layout [kkh(2)][n'(16)][kkl(2)][quad(4)][n16(16)] x 8 bf16.
// granule content: W_cat[k = (kkh*2+kkl)*32 + quad*8 + j][n = n'*16+n16]
// (A-frag and B-frag lane layouts are index-symmetric, so these granules can
//  serve as A-fragments of W_cat^T directly.)
// ---------------------------------------------------------------------------
__global__ void prep_w(const float* __restrict__ W_edge, const float* __restrict__ W_gate,
                       bf16x8* __restrict__ Wg) {
    int gid = blockIdx.x * blockDim.x + threadIdx.x;   // 0..4095
    int n16  = gid & 15;
    int quad = (gid >> 4) & 3;
    int kkl  = (gid >> 6) & 1;
    int np   = (gid >> 7) & 15;
    int kkh  = (gid >> 11) & 1;
    int n = np * 16 + n16;
    int k0 = (kkh * 2 + kkl) * 32 + quad * 8;
    const float* src = (n < 128) ? (W_edge + n) : (W_gate + (n - 128));
    bf16x8 v;
#pragma unroll
    for (int j = 0; j < 8; ++j) v[j] = (__bf16)src[(size_t)(k0 + j) * 128];
    Wg[gid] = v;
}

// ---------------------------------------------------------------------------
// K1: h = nf@W_node + b ; Q/K/V = h@W_{q,k,v} + b   (fp32, tiny)
// Q/K/V stored as (B, NH, N, HD) for K3 locality. 8 rows per 128-thr block.
// ---------------------------------------------------------------------------
__global__ __launch_bounds__(128) void k1_proj(
    const float* __restrict__ nf,
    const float* __restrict__ Wn, const float* __restrict__ bn,
    const float* __restrict__ Wq, const float* __restrict__ bq,
    const float* __restrict__ Wk, const float* __restrict__ bk,
    const float* __restrict__ Wv, const float* __restrict__ bv,
    float* __restrict__ h_res, float* __restrict__ Q,
    float* __restrict__ K, float* __restrict__ V)
{
    __shared__ float xf[8][128];
    __shared__ float hf[8][128];
    int t = threadIdx.x;
    int r0 = blockIdx.x * 8;
    for (int r = 0; r < 8; ++r) xf[r][t] = nf[(size_t)(r0 + r) * 128 + t];
    __syncthreads();
    float acc[8];
#pragma unroll
    for (int r = 0; r < 8; ++r) acc[r] = bn[t];
    for (int k = 0; k < 128; ++k) {
        float w = Wn[k * 128 + t];
#pragma unroll
        for (int r = 0; r < 8; ++r) acc[r] += xf[r][k] * w;
    }
    for (int r = 0; r < 8; ++r) { h_res[(size_t)(r0 + r) * 128 + t] = acc[r]; hf[r][t] = acc[r]; }
    __syncthreads();
    const float* Ws[3] = {Wq, Wk, Wv};
    const float* bs[3] = {bq, bk, bv};
    float* Os[3] = {Q, K, V};
#pragma unroll
    for (int m = 0; m < 3; ++m) {
        float a2[8];
#pragma unroll
        for (int r = 0; r < 8; ++r) a2[r] = bs[m][t];
        for (int k = 0; k < 128; ++k) {
            float w = Ws[m][k * 128 + t];
#pragma unroll
            for (int r = 0; r < 8; ++r) a2[r] += hf[r][k] * w;
        }
        int hh = t >> 4, d = t & 15;
        for (int r = 0; r < 8; ++r) {
            int g = r0 + r;
            int b = g / NN, i = g - b * NN;
            Os[m][(size_t)((b * NHEADS + hh) * NN + i) * HD + d] = a2[r];
        }
    }
}

// ---------------------------------------------------------------------------
// K2: edge_attn[b,h,i,j] = sum_d ( (E@W_edge+b_e) * sigmoid(E@W_gate+b_g) )
// MFMA bf16 16x16x32 with SWAPPED operands: C[hid][edge] = W_cat^T (A) x E^T (B).
// C layout (col=lane&15, row=quad*4+r) puts 4 d-values of ONE head for ONE
// edge in each lane -> the gated product + d-reduction is 3 in-reg adds +
// 2 shuffles per OUTPUT. Wave w owns head w (h-tile w, gate-tile w+8).
// W fragments live in registers; LDS holds the full 128x128 E tile (32 KB)
// -> ONE barrier per block.
// ---------------------------------------------------------------------------
__global__ __launch_bounds__(512, 4) void k2_edge(
    const float* __restrict__ EF, const bf16x8* __restrict__ Wg,
    const float* __restrict__ b_edge, const float* __restrict__ b_gate,
    float* __restrict__ edge_attn)
{
    __shared__ bf16x8 Ash[2048];   // 32 KB: full 128(M) x 128(K) E tile
    int t = threadIdx.x;
    int lane = t & 63;
    int w = t >> 6;                // wave id == head id
    int e_base = blockIdx.x * 128;

    bf16x8 wfh[4], wfg[4];
#pragma unroll
    for (int kk = 0; kk < 4; ++kk) {
        int kkh = kk >> 1, kkl = kk & 1;
        wfh[kk] = Wg[kkh * 2048 + ( w      * 2 + kkl) * 64 + lane];
        wfg[kk] = Wg[kkh * 2048 + ((w + 8) * 2 + kkl) * 64 + lane];
    }

#pragma unroll
    for (int p = 0; p < 4; ++p) {
        int gid = p * 512 + t;
        int m16 = gid & 15, quad = (gid >> 4) & 3, kk = (gid >> 6) & 3, ip = gid >> 8;
        int row = ip * 16 + m16;
        const float4* src4 = (const float4*)(EF + (size_t)(e_base + row) * 128
                                             + kk * 32 + quad * 8);
        float4 f0 = src4[0], f1 = src4[1];
        bf16x8 v;
        v[0] = (__bf16)f0.x; v[1] = (__bf16)f0.y; v[2] = (__bf16)f0.z; v[3] = (__bf16)f0.w;
        v[4] = (__bf16)f1.x; v[5] = (__bf16)f1.y; v[6] = (__bf16)f1.z; v[7] = (__bf16)f1.w;
        Ash[gid] = v;
    }
    __syncthreads();

    f32x4 acc_h[8], acc_g[8];
    f32x4 zero = {0.f, 0.f, 0.f, 0.f};
#pragma unroll
    for (int ip = 0; ip < 8; ++ip) { acc_h[ip] = zero; acc_g[ip] = zero; }

#pragma unroll
    for (int kk = 0; kk < 4; ++kk) {
#pragma unroll
        for (int ip = 0; ip < 8; ++ip) {
            bf16x8 be = Ash[(ip * 4 + kk) * 64 + lane];
            acc_h[ip] = __builtin_amdgcn_mfma_f32_16x16x32_bf16(wfh[kk], be, acc_h[ip], 0, 0, 0);
            acc_g[ip] = __builtin_amdgcn_mfma_f32_16x16x32_bf16(wfg[kk], be, acc_g[ip], 0, 0, 0);
        }
    }

    int n16 = lane & 15, quad = lane >> 4;
    float bh[4], bg[4];
#pragma unroll
    for (int r = 0; r < 4; ++r) {
        bh[r] = b_edge[w * 16 + quad * 4 + r];
        bg[r] = b_gate[w * 16 + quad * 4 + r];
    }
#pragma unroll
    for (int ip = 0; ip < 8; ++ip) {
        float s = 0.f;
#pragma unroll
        for (int r = 0; r < 4; ++r) {
            float hv = acc_h[ip][r] + bh[r];
            float gv = acc_g[ip][r] + bg[r];
            float sig = __builtin_amdgcn_rcpf(1.f + __expf(-gv));
            s = fmaf(hv, sig, s);
        }
        s += __shfl_xor(s, 16);
        s += __shfl_xor(s, 32);
        if (quad == 0) {
            int e = e_base + ip * 16 + n16;
            int b = e / LOCAL_E;
            int local = e - b * LOCAL_E;
            edge_attn[(size_t)(b * NHEADS + w) * LOCAL_E + local] = s;
        }
    }
}

// ---------------------------------------------------------------------------
// K3: scores = QK^T/4 + edge_attn, mask, softmax, attn_out = attn@V,
// attn_mean accumulated via atomics (zeroed beforehand).
// RESTRUCTURED: one row per WAVE -> all reductions are wave shuffles, ONE
// barrier per block (after K/V staging). Block: 256 thr (4 waves) handles
// (b,h, 16 query rows); 4 rows per wave, serial.
// QK phase: lane owns j = jj*64+lane (6 cols), score in registers.
// PV phase: lane = (jg,d) = (lane>>4, lane&15), j = s*4+jg interleave ->
// rowbuf broadcast reads + unpadded Vh 2-way-free reads, 2-shuffle finish.
// ---------------------------------------------------------------------------
__global__ __launch_bounds__(256) void k3_attn(
    const float* __restrict__ Q, const float* __restrict__ K, const float* __restrict__ V,
    const float* __restrict__ edge_attn, const int* __restrict__ adj,
    float* __restrict__ am, float* __restrict__ attn_out)
{
    __shared__ float Kh[NN * 17];     // padded: QK reads stride-17 (2-way free)
    __shared__ float Vh[NN * 16];     // unpadded: vector staging, 2-way-free PV reads
    __shared__ float Qi[16 * HD];
    __shared__ float rowbuf[4][NN];
    int t = threadIdx.x;
    int lane = t & 63, wid = t >> 6;
    int bh = blockIdx.x / 24;
    int chunk = blockIdx.x % 24;
    int b = bh >> 3, h = bh & 7;
    const float4* K4 = (const float4*)(K + (size_t)bh * NN * HD);
    const float4* V4 = (const float4*)(V + (size_t)bh * NN * HD);
    // stage K (padded, scalar writes) and V (unpadded, vector writes)
#pragma unroll
    for (int p = 0; p < 6; ++p) {
        int idx4 = p * 256 + t;          // 0..1535 float4s
        int j = idx4 >> 2, d0 = (idx4 & 3) * 4;
        float4 kv = K4[idx4];
        Kh[j * 17 + d0]     = kv.x;
        Kh[j * 17 + d0 + 1] = kv.y;
        Kh[j * 17 + d0 + 2] = kv.z;
        Kh[j * 17 + d0 + 3] = kv.w;
        ((float4*)Vh)[idx4] = V4[idx4];
    }
    Qi[t] = Q[(size_t)bh * NN * HD + chunk * 16 * HD + t];
    __syncthreads();

    const float* ea = edge_attn + (size_t)bh * LOCAL_E;
    const int* adjb = adj + (size_t)b * LOCAL_E;
    float* amb = am + (size_t)b * LOCAL_E;
    int jg = lane >> 4, d = lane & 15;

    for (int r = 0; r < 4; ++r) {
        int rr = wid * 4 + r;
        int i = chunk * 16 + rr;
        float ql[16];
#pragma unroll
        for (int dd = 0; dd < 16; ++dd) ql[dd] = Qi[rr * 16 + dd];  // broadcast
        const float* ea_row = ea + (size_t)i * NN;
        const int* adj_row = adjb + (size_t)i * NN;
        float s[6];
#pragma unroll
        for (int jj = 0; jj < 6; ++jj) {
            int j = jj * 64 + lane;
            float a = 0.f;
#pragma unroll
            for (int dd = 0; dd < 16; ++dd) a = fmaf(ql[dd], Kh[j * 17 + dd], a);
            a = a * 0.25f + ea_row[j];
            if (adj_row[j] == 0) a = -1e9f;
            s[jj] = a;
        }
        float mx = s[0];
#pragma unroll
        for (int jj = 1; jj < 6; ++jj) mx = fmaxf(mx, s[jj]);
#pragma unroll
        for (int o = 1; o < 64; o <<= 1) mx = fmaxf(mx, __shfl_xor(mx, o));
        float sm = 0.f;
#pragma unroll
        for (int jj = 0; jj < 6; ++jj) { s[jj] = __expf(s[jj] - mx); sm += s[jj]; }
#pragma unroll
        for (int o = 1; o < 64; o <<= 1) sm += __shfl_xor(sm, o);
        float inv = 1.f / sm;
#pragma unroll
        for (int jj = 0; jj < 6; ++jj) {
            int j = jj * 64 + lane;
            float p = s[jj] * inv;
            rowbuf[wid][j] = p;
            atomicAdd(amb + (size_t)i * NN + j, p * 0.125f);
        }
        // PV: same-wave LDS write->read (compiler orders via lgkmcnt)
        float pa = 0.f;
#pragma unroll 4
        for (int ss = 0; ss < 96; ++ss) {
            int j = ss * 4 + jg;
            pa = fmaf(rowbuf[wid][j], Vh[j * 16 + d], pa);
        }
        pa += __shfl_xor(pa, 16);
        pa += __shfl_xor(pa, 32);
        if (lane < 16)
            attn_out[(size_t)(b * NN + i) * HIDDIM + h * HD + lane] = pa;
    }
}

// ---------------------------------------------------------------------------
// K5: h_new = LN(residual + attn_out@W_out + b_out); hp = h_new@W_eout
// ---------------------------------------------------------------------------
__global__ __launch_bounds__(128) void k5_hout(
    const float* __restrict__ attn_out, const float* __restrict__ h_res,
    const float* __restrict__ W_out, const float* __restrict__ b_out,
    const float* __restrict__ g1, const float* __restrict__ be1,
    const float* __restrict__ W_eout,
    float* __restrict__ h_out, float* __restrict__ hp)
{
    __shared__ float ao[8][128];
    __shared__ float hn[8][128];
    __shared__ float redA[2], redB[2];
    int t = threadIdx.x, r0 = blockIdx.x * 8;
    for (int r = 0; r < 8; ++r) ao[r][t] = attn_out[(size_t)(r0 + r) * 128 + t];
    __syncthreads();
    float acc[8];
#pragma unroll
    for (int r = 0; r < 8; ++r) acc[r] = b_out[t];
    for (int k = 0; k < 128; ++k) {
        float w = W_out[k * 128 + t];
#pragma unroll
        for (int r = 0; r < 8; ++r) acc[r] += ao[r][k] * w;
    }
    int lane = t & 63, wid = t >> 6;
    float gg = g1[t], bb = be1[t];
    for (int r = 0; r < 8; ++r) {
        float u = h_res[(size_t)(r0 + r) * 128 + t] + acc[r];
        float sv = u, sq = u * u;
#pragma unroll
        for (int o = 1; o < 64; o <<= 1) { sv += __shfl_xor(sv, o); sq += __shfl_xor(sq, o); }
        if (lane == 0) { redA[wid] = sv; redB[wid] = sq; }
        __syncthreads();
        float tot = redA[0] + redA[1], totq = redB[0] + redB[1];
        __syncthreads();
        float mean = tot * (1.f / 128.f);
        float var = totq * (1.f / 128.f) - mean * mean;
        float nv = (u - mean) * rsqrtf(var + 1e-5f) * gg + bb;
        h_out[(size_t)(r0 + r) * 128 + t] = nv;
        hn[r][t] = nv;
    }
    __syncthreads();
    float acc2[8];
#pragma unroll
    for (int r = 0; r < 8; ++r) acc2[r] = 0.f;
    for (int k = 0; k < 128; ++k) {
        float w = W_eout[k * 128 + t];
#pragma unroll
        for (int r = 0; r < 8; ++r) acc2[r] += hn[r][k] * w;
    }
    for (int r = 0; r < 8; ++r) hp[(size_t)(r0 + r) * 128 + t] = acc2[r];
}

// ---------------------------------------------------------------------------
// K6: edge_out = LN(edge_feat + am*0.5*(hp_i+hp_j) + b_eout)  (HBM-bound)
// 8 edges per 256-thr block; 32 lanes x float4 per edge.
// ---------------------------------------------------------------------------
__global__ __launch_bounds__(256) void k6_eout(
    const float* __restrict__ EF, const float* __restrict__ am,
    const float* __restrict__ hp, const float* __restrict__ b_eout,
    const float* __restrict__ g2, const float* __restrict__ be2,
    float* __restrict__ eout)
{
    int t = threadIdx.x;
    int slot = t >> 5, l = t & 31;
    int e = blockIdx.x * 8 + slot;
    int b = e / LOCAL_E;
    int local = e - b * LOCAL_E;
    int i = local / NN, j = local - i * NN;
    float a = am[e];
    const float4* ef4 = (const float4*)(EF + (size_t)e * 128);
    const float4* hpi = (const float4*)(hp + (size_t)(b * NN + i) * 128);
    const float4* hpj = (const float4*)(hp + (size_t)(b * NN + j) * 128);
    float4 ef = ef4[l];
    float4 pi = hpi[l], pj = hpj[l];
    float4 bo = ((const float4*)b_eout)[l];
    float4 u;
    u.x = ef.x + a * 0.5f * (pi.x + pj.x) + bo.x;
    u.y = ef.y + a * 0.5f * (pi.y + pj.y) + bo.y;
    u.z = ef.z + a * 0.5f * (pi.z + pj.z) + bo.z;
    u.w = ef.w + a * 0.5f * (pi.w + pj.w) + bo.w;
    float sv = u.x + u.y + u.z + u.w;
    float sq = u.x * u.x + u.y * u.y + u.z * u.z + u.w * u.w;
#pragma unroll
    for (int o = 1; o < 32; o <<= 1) { sv += __shfl_xor(sv, o); sq += __shfl_xor(sq, o); }
    float mean = sv * (1.f / 128.f);
    float var = sq * (1.f / 128.f) - mean * mean;
    float rs = rsqrtf(var + 1e-5f);
    float4 gg = ((const float4*)g2)[l], bb = ((const float4*)be2)[l];
    float4 o4;
    o4.x = (u.x - mean) * rs * gg.x + bb.x;
    o4.y = (u.y - mean) * rs * gg.y + bb.y;
    o4.z = (u.z - mean) * rs * gg.z + bb.z;
    o4.w = (u.w - mean) * rs * gg.w + bb.w;
    ((float4*)(eout + (size_t)e * 128))[l] = o4;
}

extern "C" void kernel_launch(void* const* d_in, const int* in_sizes, int n_in,
                              void* d_out, int out_size, void* d_ws, size_t ws_size,
                              hipStream_t stream) {
    (void)in_sizes; (void)n_in; (void)out_size; (void)ws_size;
    const float* nf     = (const float*)d_in[0];
    const float* ef     = (const float*)d_in[1];
    const int*   adj    = (const int*)d_in[2];
    const float* W_node = (const float*)d_in[3];
    const float* b_node = (const float*)d_in[4];
    const float* W_q    = (const float*)d_in[5];
    const float* b_q    = (const float*)d_in[6];
    const float* W_k    = (const float*)d_in[7];
    const float* b_k    = (const float*)d_in[8];
    const float* W_v    = (const float*)d_in[9];
    const float* b_v    = (const float*)d_in[10];
    const float* W_edge = (const float*)d_in[11];
    const float* b_edge = (const float*)d_in[12];
    const float* W_gate = (const float*)d_in[13];
    const float* b_gate = (const float*)d_in[14];
    const float* W_out  = (const float*)d_in[15];
    const float* b_out  = (const float*)d_in[16];
    const float* W_eout = (const float*)d_in[17];
    const float* b_eout = (const float*)d_in[18];
    const float* g1     = (const float*)d_in[19];
    const float* be1    = (const float*)d_in[20];
    const float* g2     = (const float*)d_in[21];
    const float* be2    = (const float*)d_in[22];

    float* ws = (float*)d_ws;
    float* h_res    = ws;                 //  98304
    float* Q        = ws + 98304;         //  98304
    float* Kp       = ws + 196608;        //  98304
    float* Vp       = ws + 294912;        //  98304
    float* attn_out = ws + 393216;        //  98304
    float* hp       = ws + 491520;        //  98304
    float* am       = ws + 589824;        // 294912
    bf16x8* Wg      = (bf16x8*)(ws + 884736); // 64 KB, 16B-aligned

    float* h_out = (float*)d_out;                  // output 0: (B,N,HID)
    float* eout  = (float*)d_out + 98304;          // output 1: (B,N,N,EDGE_DIM)
    // edge_attn scratch parked inside the (not-yet-written) edge output region
    float* edge_attn = eout;                       // 2359296 floats, K6 overwrites later

    prep_w<<<dim3(16), dim3(256), 0, stream>>>(W_edge, W_gate, Wg);
    k1_proj<<<dim3(96), dim3(128), 0, stream>>>(nf, W_node, b_node, W_q, b_q,
                                                W_k, b_k, W_v, b_v, h_res, Q, Kp, Vp);
    k2_edge<<<dim3(2304), dim3(512), 0, stream>>>(ef, Wg, b_edge, b_gate, edge_attn);
    hipMemsetAsync((void*)am, 0, (size_t)NE * sizeof(float), stream);
    k3_attn<<<dim3(384), dim3(256), 0, stream>>>(Q, Kp, Vp, edge_attn, adj, am, attn_out);
    k5_hout<<<dim3(96), dim3(128), 0, stream>>>(attn_out, h_res, W_out, b_out,
                                                g1, be1, W_eout, h_out, hp);
    k6_eout<<<dim3(36864), dim3(256), 0, stream>>>(ef, am, hp, b_eout, g2, be2, eout);
}